// Round 9
// baseline (313.981 us; speedup 1.0000x reference)
//
#include <hip/hip_runtime.h>

typedef _Float16 v2h __attribute__((ext_vector_type(2)));

#define BB 128
#define TT 512
#define NN 200
#define START_IDX 1
#define END_IDX 2

#define NT 512        // 8 waves
#define QI 28         // valid halves per chunk (chunk owner c = lane&7)
#define CH 40         // padded halves per chunk: 80B stride, conflict-free bank sets
#define PSLOTS (8*CH) // 320

__device__ __forceinline__ float fdot2(v2h a, v2h b, float c) {
  return __builtin_amdgcn_fdot2(a, b, c, false);
}

// LDS-only barrier: does NOT drain vmcnt (global u-prefetch stays in flight).
__device__ __forceinline__ void sync_lds() {
  asm volatile("s_waitcnt lgkmcnt(0)" ::: "memory");
  __builtin_amdgcn_s_barrier();
  __builtin_amdgcn_sched_barrier(0);
}

// sum over 8 consecutive lanes (same lane>>3); all 8 lanes get the sum
__device__ __forceinline__ float dpp_add8(float x) {
  int v;
  v = __builtin_amdgcn_mov_dpp(__float_as_int(x), 0xB1, 0xF, 0xF, true);  // quad xor1
  x += __int_as_float(v);
  v = __builtin_amdgcn_mov_dpp(__float_as_int(x), 0x4E, 0xF, 0xF, true);  // quad xor2
  x += __int_as_float(v);
  v = __builtin_amdgcn_mov_dpp(__float_as_int(x), 0x141, 0xF, 0xF, true); // row_half_mirror
  x += __int_as_float(v);
  return x;
}

// max over 8 consecutive lanes; all 8 lanes get the max
__device__ __forceinline__ float dpp_max8(float x) {
  int v;
  v = __builtin_amdgcn_mov_dpp(__float_as_int(x), 0xB1, 0xF, 0xF, true);
  x = fmaxf(x, __int_as_float(v));
  v = __builtin_amdgcn_mov_dpp(__float_as_int(x), 0x4E, 0xF, 0xF, true);
  x = fmaxf(x, __int_as_float(v));
  v = __builtin_amdgcn_mov_dpp(__float_as_int(x), 0x141, 0xF, 0xF, true);
  x = fmaxf(x, __int_as_float(v));
  return x;
}

// full-wave sum, pure DPP; result valid in lane 63
__device__ __forceinline__ float wave_sum_dpp(float x) {
  int v;
  v = __builtin_amdgcn_mov_dpp(__float_as_int(x), 0xB1, 0xF, 0xF, true);
  x += __int_as_float(v);
  v = __builtin_amdgcn_mov_dpp(__float_as_int(x), 0x4E, 0xF, 0xF, true);
  x += __int_as_float(v);
  v = __builtin_amdgcn_mov_dpp(__float_as_int(x), 0x141, 0xF, 0xF, true);
  x += __int_as_float(v);
  v = __builtin_amdgcn_mov_dpp(__float_as_int(x), 0x140, 0xF, 0xF, true); // row_mirror
  x += __int_as_float(v);
  v = __builtin_amdgcn_mov_dpp(__float_as_int(x), 0x142, 0xF, 0xF, true); // bcast15
  x += __int_as_float(v);
  v = __builtin_amdgcn_mov_dpp(__float_as_int(x), 0x143, 0xF, 0xF, true); // bcast31
  x += __int_as_float(v);
  return x;
}

// full-wave max (nonneg inputs), pure DPP; result valid in lane 63
__device__ __forceinline__ float wave_max_dpp(float x) {
  int v;
  v = __builtin_amdgcn_mov_dpp(__float_as_int(x), 0xB1, 0xF, 0xF, true);
  x = fmaxf(x, __int_as_float(v));
  v = __builtin_amdgcn_mov_dpp(__float_as_int(x), 0x4E, 0xF, 0xF, true);
  x = fmaxf(x, __int_as_float(v));
  v = __builtin_amdgcn_mov_dpp(__float_as_int(x), 0x141, 0xF, 0xF, true);
  x = fmaxf(x, __int_as_float(v));
  v = __builtin_amdgcn_mov_dpp(__float_as_int(x), 0x140, 0xF, 0xF, true);
  x = fmaxf(x, __int_as_float(v));
  v = __builtin_amdgcn_mov_dpp(__float_as_int(x), 0x142, 0xF, 0xF, true);
  x = fmaxf(x, __int_as_float(v));
  v = __builtin_amdgcn_mov_dpp(__float_as_int(x), 0x143, 0xF, 0xF, true);
  x = fmaxf(x, __int_as_float(v));
  return x;
}

__global__ __attribute__((amdgpu_flat_work_group_size(NT, NT),
                          amdgpu_waves_per_eu(2, 2)))
void crf_fwd_kernel(
    const float* __restrict__ unary, const int* __restrict__ tags,
    const int* __restrict__ lengths, const float* __restrict__ trans,
    float* __restrict__ ws) {
  const int b = blockIdx.x;
  const int tid = threadIdx.x;
  const int lane = tid & 63;
  const int wave = tid >> 6;
  const int c = lane & 7;          // i-chunk: i in [28c, 28c+28)
  const int g = (lane >> 3) & 7;   // local group within wave
  const int jg = (wave << 3) + g;  // global group id [0,64)
  const int len = lengths[b];

  // p in fp16, 80B chunk stride. Pad halves 28..29 of chunk w carry (as f32
  // bits) wave w's partial row-max of this buffer's p -- the scale rides the
  // q3 read. NOTE: those bits must NEVER be read as fp16 (0 x Inf = NaN);
  // the qx offset below is clamped so g=7 lanes read data halves instead.
  __shared__ __align__(16) _Float16 pH[2][PSLOTS];
  // Occupancy pin: 92KB forces 1 block/CU. big[0..7]=red, big[8..15]=redE, big[16]=goldS.
  __shared__ __align__(16) float big[23040];

  const float* up = unary + (size_t)b * (TT * NN);

  // ---- init: p0 = 1 at START (chunk 0 slot 1), 0 elsewhere; pads zeroed
  if (tid < PSLOTS) {
    pH[0][tid] = (tid == START_IDX) ? (_Float16)1.0f : (_Float16)0.0f;
    pH[1][tid] = (_Float16)0.0f;
  }
  __syncthreads(); // pad f32 stores below alias the array; order them after
  if (tid < 8) {   // all partial-max pads of buffer 0 = 1.0 (true max of p0)
    *reinterpret_cast<float*>(&pH[0][tid * CH + 28]) = 1.0f;
  }
  if (len < 0) big[23039] = 0.f; // keeps the pad array alive

  // ---- E = exp(trans) fp16: group jg owns rows 3*jg+r (r<3) -> rows 0..191
  v2h Er[3][QI / 2];
#pragma unroll
  for (int r = 0; r < 3; ++r) {
    const int j = 3 * jg + r; // < 192 always
    if (c < 7) {
      const float4* t4 = reinterpret_cast<const float4*>(trans + j * NN + c * QI);
#pragma unroll
      for (int k = 0; k < 7; ++k) {
        const float4 tv = t4[k];
        Er[r][2 * k + 0] = v2h{(_Float16)__expf(tv.x), (_Float16)__expf(tv.y)};
        Er[r][2 * k + 1] = v2h{(_Float16)__expf(tv.z), (_Float16)__expf(tv.w)};
      }
    } else { // only i = 196..199 valid
      const float4 tv = *reinterpret_cast<const float4*>(trans + j * NN + 196);
      Er[r][0] = v2h{(_Float16)__expf(tv.x), (_Float16)__expf(tv.y)};
      Er[r][1] = v2h{(_Float16)__expf(tv.z), (_Float16)__expf(tv.w)};
#pragma unroll
      for (int k = 2; k < QI / 2; ++k) Er[r][k] = v2h{(_Float16)0, (_Float16)0};
    }
  }
  // ---- extra row jx = 192+wave, distributed over the whole wave:
  //      lane (c,g) covers columns i = 28c + 4g .. +3 (g<7)
  const int jx = 192 + wave;
  v2h ExA = v2h{(_Float16)0, (_Float16)0}, ExB = v2h{(_Float16)0, (_Float16)0};
  if (g < 7 && (c < 7 || g == 0)) {
    const float4 tv = *reinterpret_cast<const float4*>(trans + jx * NN + c * QI + 4 * g);
    ExA = v2h{(_Float16)__expf(tv.x), (_Float16)__expf(tv.y)};
    ExB = v2h{(_Float16)__expf(tv.z), (_Float16)__expf(tv.w)};
  }
  // qx offset: g=7 lanes (Ex==0) must NOT touch pad halves 28..31 -> clamp to 0.
  const int gxo = (g < 7) ? 4 * g : 0;

  // ---- gold path score (one t per thread)
  float gacc = 0.0f;
  if (tid < len) {
    const int cur = tags[b * TT + tid];
    const int prev = (tid == 0) ? START_IDX : tags[b * TT + tid - 1];
    gacc = trans[cur * NN + prev] + up[(size_t)tid * NN + cur];
  }
#pragma unroll
  for (int k = 32; k >= 1; k >>= 1) gacc += __shfl_xor(gacc, k, 64);
  if (lane == 0) big[wave] = gacc;
  __syncthreads();
  if (tid == 0) {
    const int lt = tags[b * TT + len - 1];
    float gs = big[0];
#pragma unroll
    for (int w = 1; w < 8; ++w) gs += big[w];
    big[16] = gs + trans[END_IDX * NN + lt];
  }

  // ---- epilogue ownership: lanes c<3 -> row 3*jg+c; lane 63 -> row 192+wave
  const bool erow = (c < 3) || (lane == 63);
  const int jrow = (lane == 63) ? jx : (3 * jg + c);
  const int wh = (jrow / QI) * CH + (jrow % QI);

  // u pipeline: load 2 ahead, exp 1 ahead
  float uexpC = 0.f, uN = 0.f;
  if (erow) {
    uexpC = __expf(up[jrow]);
    uN = up[(size_t)NN + jrow];
  }
  float A = 0.0f; // running scale: alpha = A + log(p)
  __syncthreads();

  // ---- main scan: one LDS-only barrier per step
  for (int t = 0; t < len; ++t) {
    const int rb = t & 1, wb = rb ^ 1;

    // issue all LDS reads up front (q3.z carries chunk c's partial max of p_t)
    const _Float16* pc = &pH[rb][c * CH];
    const uint4 q0 = reinterpret_cast<const uint4*>(pc)[0];
    const uint4 q1 = reinterpret_cast<const uint4*>(pc)[1];
    const uint4 q2 = reinterpret_cast<const uint4*>(pc)[2];
    const uint4 q3 = *reinterpret_cast<const uint4*>(pc + 24); // data 24..27 + pad
    const uint2 qx = *reinterpret_cast<const uint2*>(&pH[rb][c * CH + gxo]);

    // scale: full max(p_t) = max of the 8 per-wave partials, one per chunk.
    // Lanes 0..7 of each DPP row hold chunks 0..7's partials -> dpp_max8.
    const float M = dpp_max8(__int_as_float(q3.z));
    const float rcpM = __builtin_amdgcn_rcpf(M);
    A += __logf(M);

    // off-path: u pipeline (global load stays in flight across the barrier)
    float L = 0.f;
    if (erow) {
      const int ti = (t + 2 < len) ? (t + 2) : (len - 1);
      L = up[(size_t)ti * NN + jrow];
    }
    const float uexpN = erow ? __expf(uN) : 0.f;
    const float f = uexpC * rcpM;

    // critical path: S = E * p (fp16 dot2, fp32 accumulate)
    const unsigned pw[14] = {q0.x, q0.y, q0.z, q0.w, q1.x, q1.y, q1.z, q1.w,
                             q2.x, q2.y, q2.z, q2.w, q3.x, q3.y};
    float a0 = 0.f, a1 = 0.f, a2 = 0.f;
#pragma unroll
    for (int k = 0; k < QI / 2; ++k) {
      const v2h pk = __builtin_bit_cast(v2h, pw[k]);
      a0 = fdot2(Er[0][k], pk, a0);
      a1 = fdot2(Er[1][k], pk, a1);
      a2 = fdot2(Er[2][k], pk, a2);
    }
    float ax = fdot2(ExA, __builtin_bit_cast(v2h, qx.x), 0.f);
    ax = fdot2(ExB, __builtin_bit_cast(v2h, qx.y), ax);

    const float s0 = dpp_add8(a0);
    const float s1 = dpp_add8(a1);
    const float s2 = dpp_add8(a2);
    const float sx = wave_sum_dpp(ax); // lane 63 valid
    float s = s0;
    s = (c == 1) ? s1 : s;
    s = (c == 2) ? s2 : s;
    s = (lane == 63) ? sx : s;

    const float pnew = s * f; // S * exp(u) / M
    if (erow) pH[wb][wh] = (_Float16)pnew; // write early: overlaps max chain
    // partial max over this wave's regular rows (extra rows excluded; bounded)
    const float mi = (erow && lane != 63) ? pnew : 0.f;
    const float mx = wave_max_dpp(mi); // lane 63 valid
    if (lane == 63)
      *reinterpret_cast<float*>(&pH[wb][wave * CH + 28]) = mx; // chunk-w pad

    uexpC = uexpN; uN = L;
    sync_lds();
  }

  // ---- terminal: alpha = A + log(p); logsumexp_j(alpha + trans[END,j])
  const int fb = len & 1;
  float v = -3e38f;
  if (tid < NN) {
    const float pv = (float)pH[fb][(tid / QI) * CH + (tid % QI)];
    const float lp = (pv > 0.f) ? __logf(pv) : -1e30f;
    v = A + lp + trans[END_IDX * NN + tid];
  }
  float mm = v;
#pragma unroll
  for (int k = 32; k >= 1; k >>= 1) mm = fmaxf(mm, __shfl_xor(mm, k, 64));
  if (lane == 0) big[wave] = mm;
  __syncthreads();
  mm = big[0];
#pragma unroll
  for (int w = 1; w < 8; ++w) mm = fmaxf(mm, big[w]);
  float e = (tid < NN) ? __expf(v - mm) : 0.0f;
#pragma unroll
  for (int k = 32; k >= 1; k >>= 1) e += __shfl_xor(e, k, 64);
  if (lane == 0) big[8 + wave] = e;
  __syncthreads();
  if (tid == 0) {
    float es = big[8];
#pragma unroll
    for (int w = 1; w < 8; ++w) es += big[8 + w];
    ws[b] = (mm + __logf(es)) - big[16];
  }
}

__global__ void crf_reduce_kernel(const float* __restrict__ wsIn,
                                  float* __restrict__ out) {
  const int tid = threadIdx.x; // 128 threads
  float v = wsIn[tid];
#pragma unroll
  for (int k = 32; k >= 1; k >>= 1) v += __shfl_xor(v, k, 64);
  __shared__ float s2[2];
  if ((tid & 63) == 0) s2[tid >> 6] = v;
  __syncthreads();
  if (tid == 0) out[0] = (s2[0] + s2[1]) * (1.0f / 128.0f);
}

extern "C" void kernel_launch(void* const* d_in, const int* in_sizes, int n_in,
                              void* d_out, int out_size, void* d_ws, size_t ws_size,
                              hipStream_t stream) {
  const float* unary = (const float*)d_in[0];
  const int* tags = (const int*)d_in[1];
  const int* lengths = (const int*)d_in[2];
  const float* trans = (const float*)d_in[3];
  float* ws = (float*)d_ws;
  float* out = (float*)d_out;

  crf_fwd_kernel<<<BB, NT, 0, stream>>>(unary, tags, lengths, trans, ws);
  crf_reduce_kernel<<<1, 128, 0, stream>>>(ws, out);
}

// Round 10
// 281.514 us; speedup vs baseline: 1.1153x; 1.1153x over previous
//
#include <hip/hip_runtime.h>

typedef _Float16 v2h __attribute__((ext_vector_type(2)));

#define BB 128
#define TT 512
#define NN 200
#define START_IDX 1
#define END_IDX 2

#define NT 512        // 8 waves
#define QI 28         // valid halves per chunk (chunk owner c = lane&7)
#define CH 40         // padded halves per chunk: 80B stride, conflict-free bank sets
#define PSLOTS (8*CH) // 320

__device__ __forceinline__ float fdot2(v2h a, v2h b, float c) {
  return __builtin_amdgcn_fdot2(a, b, c, false);
}

// LDS-only barrier: does NOT drain vmcnt (global u-prefetch stays in flight).
// The "memory"-clobber asm already orders LDS ops; no sched_barrier needed.
__device__ __forceinline__ void sync_lds() {
  asm volatile("s_waitcnt lgkmcnt(0)" ::: "memory");
  __builtin_amdgcn_s_barrier();
}

// sum over 8 consecutive lanes (same lane>>3); all 8 lanes get the sum
__device__ __forceinline__ float dpp_add8(float x) {
  int v;
  v = __builtin_amdgcn_mov_dpp(__float_as_int(x), 0xB1, 0xF, 0xF, true);  // quad xor1
  x += __int_as_float(v);
  v = __builtin_amdgcn_mov_dpp(__float_as_int(x), 0x4E, 0xF, 0xF, true);  // quad xor2
  x += __int_as_float(v);
  v = __builtin_amdgcn_mov_dpp(__float_as_int(x), 0x141, 0xF, 0xF, true); // row_half_mirror
  x += __int_as_float(v);
  return x;
}

// max over 8 consecutive lanes; all 8 lanes get the max
__device__ __forceinline__ float dpp_max8(float x) {
  int v;
  v = __builtin_amdgcn_mov_dpp(__float_as_int(x), 0xB1, 0xF, 0xF, true);
  x = fmaxf(x, __int_as_float(v));
  v = __builtin_amdgcn_mov_dpp(__float_as_int(x), 0x4E, 0xF, 0xF, true);
  x = fmaxf(x, __int_as_float(v));
  v = __builtin_amdgcn_mov_dpp(__float_as_int(x), 0x141, 0xF, 0xF, true);
  x = fmaxf(x, __int_as_float(v));
  return x;
}

// full-wave sum, pure DPP; result valid in lane 63
__device__ __forceinline__ float wave_sum_dpp(float x) {
  int v;
  v = __builtin_amdgcn_mov_dpp(__float_as_int(x), 0xB1, 0xF, 0xF, true);
  x += __int_as_float(v);
  v = __builtin_amdgcn_mov_dpp(__float_as_int(x), 0x4E, 0xF, 0xF, true);
  x += __int_as_float(v);
  v = __builtin_amdgcn_mov_dpp(__float_as_int(x), 0x141, 0xF, 0xF, true);
  x += __int_as_float(v);
  v = __builtin_amdgcn_mov_dpp(__float_as_int(x), 0x140, 0xF, 0xF, true); // row_mirror
  x += __int_as_float(v);
  v = __builtin_amdgcn_mov_dpp(__float_as_int(x), 0x142, 0xF, 0xF, true); // bcast15
  x += __int_as_float(v);
  v = __builtin_amdgcn_mov_dpp(__float_as_int(x), 0x143, 0xF, 0xF, true); // bcast31
  x += __int_as_float(v);
  return x;
}

// full-wave max (nonneg inputs), pure DPP; result valid in lane 63
__device__ __forceinline__ float wave_max_dpp(float x) {
  int v;
  v = __builtin_amdgcn_mov_dpp(__float_as_int(x), 0xB1, 0xF, 0xF, true);
  x = fmaxf(x, __int_as_float(v));
  v = __builtin_amdgcn_mov_dpp(__float_as_int(x), 0x4E, 0xF, 0xF, true);
  x = fmaxf(x, __int_as_float(v));
  v = __builtin_amdgcn_mov_dpp(__float_as_int(x), 0x141, 0xF, 0xF, true);
  x = fmaxf(x, __int_as_float(v));
  v = __builtin_amdgcn_mov_dpp(__float_as_int(x), 0x140, 0xF, 0xF, true);
  x = fmaxf(x, __int_as_float(v));
  v = __builtin_amdgcn_mov_dpp(__float_as_int(x), 0x142, 0xF, 0xF, true);
  x = fmaxf(x, __int_as_float(v));
  v = __builtin_amdgcn_mov_dpp(__float_as_int(x), 0x143, 0xF, 0xF, true);
  x = fmaxf(x, __int_as_float(v));
  return x;
}

__global__ __attribute__((amdgpu_flat_work_group_size(NT, NT),
                          amdgpu_waves_per_eu(2, 2)))
void crf_fwd_kernel(
    const float* __restrict__ unary, const int* __restrict__ tags,
    const int* __restrict__ lengths, const float* __restrict__ trans,
    float* __restrict__ ws) {
  const int b = blockIdx.x;
  const int tid = threadIdx.x;
  const int lane = tid & 63;
  const int wave = tid >> 6;
  const int c = lane & 7;          // i-chunk: i in [28c, 28c+28)
  const int g = (lane >> 3) & 7;   // local group within wave
  const int jg = (wave << 3) + g;  // global group id [0,64)
  const int len = lengths[b];

  // p in fp16, 80B chunk stride. Pad halves 28..29 of chunk w carry (as f32
  // bits) wave w's partial row-max of this buffer's p -- the scale rides the
  // q3 read. NOTE: those bits must NEVER be read as fp16 (0 x Inf = NaN);
  // the qx offset below is clamped so g=7 lanes read data halves instead.
  __shared__ __align__(16) _Float16 pH[2][PSLOTS];
  // Occupancy pin: 92KB forces 1 block/CU. big[0..7]=red, big[8..15]=redE, big[16]=goldS.
  __shared__ __align__(16) float big[23040];

  const float* up = unary + (size_t)b * (TT * NN);

  // ---- init: p0 = 1 at START (chunk 0 slot 1), 0 elsewhere; pads zeroed
  if (tid < PSLOTS) {
    pH[0][tid] = (tid == START_IDX) ? (_Float16)1.0f : (_Float16)0.0f;
    pH[1][tid] = (_Float16)0.0f;
  }
  __syncthreads(); // pad f32 stores below alias the array; order them after
  if (tid < 8) {   // all partial-max pads of buffer 0 = 1.0 (true max of p0)
    *reinterpret_cast<float*>(&pH[0][tid * CH + 28]) = 1.0f;
  }
  if (len < 0) big[23039] = 0.f; // keeps the pad array alive

  // ---- E = exp(trans) fp16: group jg owns rows 3*jg+r (r<3) -> rows 0..191
  v2h Er[3][QI / 2];
#pragma unroll
  for (int r = 0; r < 3; ++r) {
    const int j = 3 * jg + r; // < 192 always
    if (c < 7) {
      const float4* t4 = reinterpret_cast<const float4*>(trans + j * NN + c * QI);
#pragma unroll
      for (int k = 0; k < 7; ++k) {
        const float4 tv = t4[k];
        Er[r][2 * k + 0] = v2h{(_Float16)__expf(tv.x), (_Float16)__expf(tv.y)};
        Er[r][2 * k + 1] = v2h{(_Float16)__expf(tv.z), (_Float16)__expf(tv.w)};
      }
    } else { // only i = 196..199 valid
      const float4 tv = *reinterpret_cast<const float4*>(trans + j * NN + 196);
      Er[r][0] = v2h{(_Float16)__expf(tv.x), (_Float16)__expf(tv.y)};
      Er[r][1] = v2h{(_Float16)__expf(tv.z), (_Float16)__expf(tv.w)};
#pragma unroll
      for (int k = 2; k < QI / 2; ++k) Er[r][k] = v2h{(_Float16)0, (_Float16)0};
    }
  }
  // ---- extra row jx = 192+wave, distributed over the whole wave:
  //      lane (c,g) covers columns i = 28c + 4g .. +3 (g<7)
  const int jx = 192 + wave;
  v2h ExA = v2h{(_Float16)0, (_Float16)0}, ExB = v2h{(_Float16)0, (_Float16)0};
  if (g < 7 && (c < 7 || g == 0)) {
    const float4 tv = *reinterpret_cast<const float4*>(trans + jx * NN + c * QI + 4 * g);
    ExA = v2h{(_Float16)__expf(tv.x), (_Float16)__expf(tv.y)};
    ExB = v2h{(_Float16)__expf(tv.z), (_Float16)__expf(tv.w)};
  }
  // qx offset: g=7 lanes (Ex==0) must NOT touch pad halves 28..31 -> clamp to 0.
  const int gxo = (g < 7) ? 4 * g : 0;

  // ---- gold path score (one t per thread)
  float gacc = 0.0f;
  if (tid < len) {
    const int cur = tags[b * TT + tid];
    const int prev = (tid == 0) ? START_IDX : tags[b * TT + tid - 1];
    gacc = trans[cur * NN + prev] + up[(size_t)tid * NN + cur];
  }
#pragma unroll
  for (int k = 32; k >= 1; k >>= 1) gacc += __shfl_xor(gacc, k, 64);
  if (lane == 0) big[wave] = gacc;
  __syncthreads();
  if (tid == 0) {
    const int lt = tags[b * TT + len - 1];
    float gs = big[0];
#pragma unroll
    for (int w = 1; w < 8; ++w) gs += big[w];
    big[16] = gs + trans[END_IDX * NN + lt];
  }

  // ---- epilogue ownership: lanes c<3 -> row 3*jg+c; lane 63 -> row 192+wave
  const bool erow = (c < 3) || (lane == 63);
  const int jrow = (lane == 63) ? jx : (3 * jg + c);
  const int wh = (jrow / QI) * CH + (jrow % QI);
  const float* upj = up + jrow;

  // u pipeline (unroll-2 renamed): at step t, ISSUE load of u[t+2] early,
  // CONSUME (exp) the register holding u[t+1] late -- ~1.7 steps of slack, so
  // the compiler's vmcnt wait never stalls on same-step L2/HBM latency.
  float uexpC = 0.f, ldA = 0.f, ldB = 0.f;
  if (erow) {
    uexpC = __expf(upj[0]);      // exp(u_0)
    ldB = upj[(size_t)NN];       // u_1 (consumed at end of step 0)
  }
  float A2 = 0.0f; // running scale in log2 domain: alpha = A2*ln2 + log(p)
  __syncthreads();

  auto STEP = [&](int t, float& consume, float& issue) {
    const int rb = t & 1, wb = rb ^ 1;

    // issue all LDS reads up front (q3.z carries chunk c's partial max of p_t)
    const _Float16* pc = &pH[rb][c * CH];
    const uint4 q0 = reinterpret_cast<const uint4*>(pc)[0];
    const uint4 q1 = reinterpret_cast<const uint4*>(pc)[1];
    const uint4 q2 = reinterpret_cast<const uint4*>(pc)[2];
    const uint4 q3 = *reinterpret_cast<const uint4*>(pc + 24); // data 24..27 + pad
    const uint2 qx = *reinterpret_cast<const uint2*>(&pH[rb][c * CH + gxo]);

    // issue next-next u load EARLY (consumed late next step)
    if (erow) {
      const int ti = (t + 2 < len) ? (t + 2) : (len - 1);
      issue = upj[(size_t)(ti * NN)];
    }

    // scale: full max(p_t) = max of the 8 per-wave partials, one per chunk.
    const float M = dpp_max8(__int_as_float(q3.z));
    const float rcpM = __builtin_amdgcn_rcpf(M);
    A2 += __log2f(M);
    const float f = uexpC * rcpM;

    // critical path: S = E * p (fp16 dot2, fp32 accumulate)
    const unsigned pw[14] = {q0.x, q0.y, q0.z, q0.w, q1.x, q1.y, q1.z, q1.w,
                             q2.x, q2.y, q2.z, q2.w, q3.x, q3.y};
    float a0 = 0.f, a1 = 0.f, a2 = 0.f;
#pragma unroll
    for (int k = 0; k < QI / 2; ++k) {
      const v2h pk = __builtin_bit_cast(v2h, pw[k]);
      a0 = fdot2(Er[0][k], pk, a0);
      a1 = fdot2(Er[1][k], pk, a1);
      a2 = fdot2(Er[2][k], pk, a2);
    }
    float ax = fdot2(ExA, __builtin_bit_cast(v2h, qx.x), 0.f);
    ax = fdot2(ExB, __builtin_bit_cast(v2h, qx.y), ax);

    const float s0 = dpp_add8(a0);
    const float s1 = dpp_add8(a1);
    const float s2 = dpp_add8(a2);
    const float sx = wave_sum_dpp(ax); // lane 63 valid
    float s = s0;
    s = (c == 1) ? s1 : s;
    s = (c == 2) ? s2 : s;
    s = (lane == 63) ? sx : s;

    const float pnew = s * f; // S * exp(u) / M
    if (erow) pH[wb][wh] = (_Float16)pnew; // write early: overlaps max chain
    // partial max over this wave's regular rows (extra rows excluded; bounded)
    const float mi = (erow && lane != 63) ? pnew : 0.f;
    const float mx = wave_max_dpp(mi); // lane 63 valid
    if (lane == 63)
      *reinterpret_cast<float*>(&pH[wb][wave * CH + 28]) = mx; // chunk-w pad

    // consume LATE: exp(u_{t+1}), loaded early LAST step -> next step's uexpC
    uexpC = erow ? __expf(consume) : 0.f;
    sync_lds();
  };

  // ---- main scan: one LDS-only barrier per step, unrolled by 2
  int t = 0;
  for (; t + 1 < len; t += 2) {
    STEP(t, ldB, ldA);
    STEP(t + 1, ldA, ldB);
  }
  if (t < len) STEP(t, ldB, ldA);

  const float A = A2 * 0.6931471805599453f;

  // ---- terminal: alpha = A + log(p); logsumexp_j(alpha + trans[END,j])
  const int fb = len & 1;
  float v = -3e38f;
  if (tid < NN) {
    const float pv = (float)pH[fb][(tid / QI) * CH + (tid % QI)];
    const float lp = (pv > 0.f) ? __logf(pv) : -1e30f;
    v = A + lp + trans[END_IDX * NN + tid];
  }
  float mm = v;
#pragma unroll
  for (int k = 32; k >= 1; k >>= 1) mm = fmaxf(mm, __shfl_xor(mm, k, 64));
  if (lane == 0) big[wave] = mm;
  __syncthreads();
  mm = big[0];
#pragma unroll
  for (int w = 1; w < 8; ++w) mm = fmaxf(mm, big[w]);
  float e = (tid < NN) ? __expf(v - mm) : 0.0f;
#pragma unroll
  for (int k = 32; k >= 1; k >>= 1) e += __shfl_xor(e, k, 64);
  if (lane == 0) big[8 + wave] = e;
  __syncthreads();
  if (tid == 0) {
    float es = big[8];
#pragma unroll
    for (int w = 1; w < 8; ++w) es += big[8 + w];
    ws[b] = (mm + __logf(es)) - big[16];
  }
}

__global__ void crf_reduce_kernel(const float* __restrict__ wsIn,
                                  float* __restrict__ out) {
  const int tid = threadIdx.x; // 128 threads
  float v = wsIn[tid];
#pragma unroll
  for (int k = 32; k >= 1; k >>= 1) v += __shfl_xor(v, k, 64);
  __shared__ float s2[2];
  if ((tid & 63) == 0) s2[tid >> 6] = v;
  __syncthreads();
  if (tid == 0) out[0] = (s2[0] + s2[1]) * (1.0f / 128.0f);
}

extern "C" void kernel_launch(void* const* d_in, const int* in_sizes, int n_in,
                              void* d_out, int out_size, void* d_ws, size_t ws_size,
                              hipStream_t stream) {
  const float* unary = (const float*)d_in[0];
  const int* tags = (const int*)d_in[1];
  const int* lengths = (const int*)d_in[2];
  const float* trans = (const float*)d_in[3];
  float* ws = (float*)d_ws;
  float* out = (float*)d_out;

  crf_fwd_kernel<<<BB, NT, 0, stream>>>(unary, tags, lengths, trans, ws);
  crf_reduce_kernel<<<1, 128, 0, stream>>>(ws, out);
}

// Round 11
// 245.298 us; speedup vs baseline: 1.2800x; 1.1476x over previous
//
#include <hip/hip_runtime.h>

typedef _Float16 v2h __attribute__((ext_vector_type(2)));

#define BB 128
#define TT 512
#define NN 200
#define START_IDX 1
#define END_IDX 2

#define NT 256        // 4 waves
#define QI 28         // valid halves per chunk (chunk owner c = lane&7)
#define CH 40         // padded halves per chunk: 80B stride, conflict-free bank sets
#define PSLOTS (8*CH) // 320

__device__ __forceinline__ float fdot2(v2h a, v2h b, float c) {
  return __builtin_amdgcn_fdot2(a, b, c, false);
}

// LDS-only barrier: does NOT drain vmcnt (global u-prefetch stays in flight).
__device__ __forceinline__ void sync_lds() {
  asm volatile("s_waitcnt lgkmcnt(0)" ::: "memory");
  __builtin_amdgcn_s_barrier();
}

// sum over 8 consecutive lanes (same lane>>3); all 8 lanes get the sum
__device__ __forceinline__ float dpp_add8(float x) {
  int v;
  v = __builtin_amdgcn_mov_dpp(__float_as_int(x), 0xB1, 0xF, 0xF, true);  // quad xor1
  x += __int_as_float(v);
  v = __builtin_amdgcn_mov_dpp(__float_as_int(x), 0x4E, 0xF, 0xF, true);  // quad xor2
  x += __int_as_float(v);
  v = __builtin_amdgcn_mov_dpp(__float_as_int(x), 0x141, 0xF, 0xF, true); // row_half_mirror
  x += __int_as_float(v);
  return x;
}

// max over 8 consecutive lanes; all 8 lanes get the max
__device__ __forceinline__ float dpp_max8(float x) {
  int v;
  v = __builtin_amdgcn_mov_dpp(__float_as_int(x), 0xB1, 0xF, 0xF, true);
  x = fmaxf(x, __int_as_float(v));
  v = __builtin_amdgcn_mov_dpp(__float_as_int(x), 0x4E, 0xF, 0xF, true);
  x = fmaxf(x, __int_as_float(v));
  v = __builtin_amdgcn_mov_dpp(__float_as_int(x), 0x141, 0xF, 0xF, true);
  x = fmaxf(x, __int_as_float(v));
  return x;
}

// full-wave max (nonneg inputs), pure DPP; result valid in lane 63
__device__ __forceinline__ float wave_max_dpp(float x) {
  int v;
  v = __builtin_amdgcn_mov_dpp(__float_as_int(x), 0xB1, 0xF, 0xF, true);
  x = fmaxf(x, __int_as_float(v));
  v = __builtin_amdgcn_mov_dpp(__float_as_int(x), 0x4E, 0xF, 0xF, true);
  x = fmaxf(x, __int_as_float(v));
  v = __builtin_amdgcn_mov_dpp(__float_as_int(x), 0x141, 0xF, 0xF, true);
  x = fmaxf(x, __int_as_float(v));
  v = __builtin_amdgcn_mov_dpp(__float_as_int(x), 0x140, 0xF, 0xF, true);
  x = fmaxf(x, __int_as_float(v));
  v = __builtin_amdgcn_mov_dpp(__float_as_int(x), 0x142, 0xF, 0xF, true);
  x = fmaxf(x, __int_as_float(v));
  v = __builtin_amdgcn_mov_dpp(__float_as_int(x), 0x143, 0xF, 0xF, true);
  x = fmaxf(x, __int_as_float(v));
  return x;
}

__global__ __attribute__((amdgpu_flat_work_group_size(NT, NT),
                          amdgpu_waves_per_eu(1, 1)))
void crf_fwd_kernel(
    const float* __restrict__ unary, const int* __restrict__ tags,
    const int* __restrict__ lengths, const float* __restrict__ trans,
    float* __restrict__ ws) {
  const int b = blockIdx.x;
  const int tid = threadIdx.x;
  const int lane = tid & 63;
  const int wave = tid >> 6;       // 0..3
  const int c = lane & 7;          // i-chunk: i in [28c, 28c+28)
  const int g = (lane >> 3) & 7;   // group within wave, 0..7
  const int gg = (wave << 3) + g;  // global group id, 0..31
  const int len = lengths[b];

  // p in fp16, 80B chunk stride. Pad halves 28..29 of chunks 0..3 carry (as
  // f32 bits) wave w's partial row-max of this buffer's p; chunks 4..7 pads
  // stay 0 forever. Pads never read as fp16.
  __shared__ __align__(16) _Float16 pH[2][PSLOTS];
  // Occupancy pin: 92KB forces 1 block/CU -> 1 wave/SIMD -> VGPR budget for
  // the 98-reg E matrix. big[0..3]=red, big[8..11]=redE, big[16]=goldS.
  __shared__ __align__(16) float big[23040];

  const float* up = unary + (size_t)b * (TT * NN);

  // ---- init: p0 = 1 at START (chunk 0 slot 1), 0 elsewhere; pads zeroed
  for (int i = tid; i < PSLOTS; i += NT) {
    pH[0][i] = (i == START_IDX) ? (_Float16)1.0f : (_Float16)0.0f;
    pH[1][i] = (_Float16)0.0f;
  }
  __syncthreads(); // pad f32 store below aliases the array; order it after
  if (tid == 0) *reinterpret_cast<float*>(&pH[0][28]) = 1.0f; // max(p0)=1
  if (len < 0) big[23039] = 0.f; // keeps the pad array alive

  // ---- E = exp(trans) fp16: group gg owns rows 6*gg+r (r<6) -> rows 0..191;
  //      groups g<2 of wave w additionally own row 192+2w+g (rows 192..199).
  v2h Er[7][QI / 2];
#pragma unroll
  for (int r = 0; r < 7; ++r) {
    int j;
    bool valid;
    if (r < 6) { j = 6 * gg + r; valid = true; }           // < 192 always
    else       { j = 192 + 2 * wave + g; valid = (g < 2); } // extra row
    if (valid) {
      if (c < 7) {
        const float4* t4 = reinterpret_cast<const float4*>(trans + j * NN + c * QI);
#pragma unroll
        for (int k = 0; k < 7; ++k) {
          const float4 tv = t4[k];
          Er[r][2 * k + 0] = v2h{(_Float16)__expf(tv.x), (_Float16)__expf(tv.y)};
          Er[r][2 * k + 1] = v2h{(_Float16)__expf(tv.z), (_Float16)__expf(tv.w)};
        }
      } else { // only i = 196..199 valid
        const float4 tv = *reinterpret_cast<const float4*>(trans + j * NN + 196);
        Er[r][0] = v2h{(_Float16)__expf(tv.x), (_Float16)__expf(tv.y)};
        Er[r][1] = v2h{(_Float16)__expf(tv.z), (_Float16)__expf(tv.w)};
#pragma unroll
        for (int k = 2; k < QI / 2; ++k) Er[r][k] = v2h{(_Float16)0, (_Float16)0};
      }
    } else {
#pragma unroll
      for (int k = 0; k < QI / 2; ++k) Er[r][k] = v2h{(_Float16)0, (_Float16)0};
    }
  }

  // ---- gold path score (<=2 t per thread)
  float gacc = 0.0f;
  for (int t = tid; t < len; t += NT) {
    const int cur = tags[b * TT + t];
    const int prev = (t == 0) ? START_IDX : tags[b * TT + t - 1];
    gacc += trans[cur * NN + prev] + up[(size_t)t * NN + cur];
  }
#pragma unroll
  for (int k = 32; k >= 1; k >>= 1) gacc += __shfl_xor(gacc, k, 64);
  if (lane == 0) big[wave] = gacc;
  __syncthreads();
  if (tid == 0) {
    const int lt = tags[b * TT + len - 1];
    big[16] = big[0] + big[1] + big[2] + big[3] + trans[END_IDX * NN + lt];
  }

  // ---- tail ownership: lanes c<6 -> row 6*gg+c; lane c==6 (g<2) -> extra row
  const bool erow = (c < 6) || (c == 6 && g < 2);
  const int jrow = (c < 6) ? (6 * gg + c) : (192 + 2 * wave + g);
  const int wh = (jrow / QI) * CH + (jrow % QI);
  const float* upj = up + jrow;

  // u pipeline (unroll-2 renamed): issue load of u[t+2] early, consume (exp)
  // u[t+1]'s register late -- ~1.7 steps of slack across the barrier.
  float uexpC = 0.f, ldA = 0.f, ldB = 0.f;
  if (erow) {
    uexpC = __expf(upj[0]);
    ldB = upj[(size_t)NN];
  }
  float A2 = 0.0f; // running scale in log2 domain: alpha = A2*ln2 + log(p)
  __syncthreads();

  auto STEP = [&](int t, float& consume, float& issue) {
    const int rb = t & 1, wb = rb ^ 1;

    // issue all LDS reads up front (q3.z carries chunk c's partial max of p_t)
    const _Float16* pc = &pH[rb][c * CH];
    const uint4 q0 = reinterpret_cast<const uint4*>(pc)[0];
    const uint4 q1 = reinterpret_cast<const uint4*>(pc)[1];
    const uint4 q2 = reinterpret_cast<const uint4*>(pc)[2];
    const uint4 q3 = *reinterpret_cast<const uint4*>(pc + 24); // data 24..27 + pads

    // issue next-next u load EARLY (consumed late next step)
    if (erow) {
      const int ti = (t + 2 < len) ? (t + 2) : (len - 1);
      issue = upj[(size_t)(ti * NN)];
    }

    // scale: full max(p_t) = max of the 4 wave-partials (chunks 4..7 pads = 0)
    const float M = dpp_max8(__int_as_float(q3.z));
    const float rcpM = __builtin_amdgcn_rcpf(M);
    A2 += __log2f(M);
    const float f = uexpC * rcpM;

    // critical path: S = E * p (fp16 dot2, fp32 accumulate), 7 rows/group
    const unsigned pw[14] = {q0.x, q0.y, q0.z, q0.w, q1.x, q1.y, q1.z, q1.w,
                             q2.x, q2.y, q2.z, q2.w, q3.x, q3.y};
    float a0 = 0.f, a1 = 0.f, a2 = 0.f, a3 = 0.f, a4 = 0.f, a5 = 0.f, a6 = 0.f;
#pragma unroll
    for (int k = 0; k < QI / 2; ++k) {
      const v2h pk = __builtin_bit_cast(v2h, pw[k]);
      a0 = fdot2(Er[0][k], pk, a0);
      a1 = fdot2(Er[1][k], pk, a1);
      a2 = fdot2(Er[2][k], pk, a2);
      a3 = fdot2(Er[3][k], pk, a3);
      a4 = fdot2(Er[4][k], pk, a4);
      a5 = fdot2(Er[5][k], pk, a5);
      a6 = fdot2(Er[6][k], pk, a6);
    }
    const float s0 = dpp_add8(a0);
    const float s1 = dpp_add8(a1);
    const float s2 = dpp_add8(a2);
    const float s3 = dpp_add8(a3);
    const float s4 = dpp_add8(a4);
    const float s5 = dpp_add8(a5);
    const float s6 = dpp_add8(a6);
    float s = s0;
    s = (c == 1) ? s1 : s;
    s = (c == 2) ? s2 : s;
    s = (c == 3) ? s3 : s;
    s = (c == 4) ? s4 : s;
    s = (c == 5) ? s5 : s;
    s = (c == 6) ? s6 : s;

    const float pnew = s * f; // S * exp(u) / M
    if (erow) pH[wb][wh] = (_Float16)pnew; // write early: overlaps max chain
    // partial max over regular rows (extra rows excluded; drift bounded)
    const float mi = (c < 6) ? pnew : 0.f;
    const float mx = wave_max_dpp(mi); // lane 63 valid
    if (lane == 63)
      *reinterpret_cast<float*>(&pH[wb][wave * CH + 28]) = mx; // chunk-w pad

    // consume LATE: exp(u_{t+1}), loaded early LAST step -> next step's uexpC
    uexpC = erow ? __expf(consume) : 0.f;
    sync_lds();
  };

  // ---- main scan: one LDS-only barrier per step, unrolled by 2
  int t = 0;
  for (; t + 1 < len; t += 2) {
    STEP(t, ldB, ldA);
    STEP(t + 1, ldA, ldB);
  }
  if (t < len) STEP(t, ldB, ldA);

  const float A = A2 * 0.6931471805599453f;

  // ---- terminal: alpha = A + log(p); logsumexp_j(alpha + trans[END,j])
  const int fb = len & 1;
  float v = -3e38f;
  if (tid < NN) {
    const float pv = (float)pH[fb][(tid / QI) * CH + (tid % QI)];
    const float lp = (pv > 0.f) ? __logf(pv) : -1e30f;
    v = A + lp + trans[END_IDX * NN + tid];
  }
  float mm = v;
#pragma unroll
  for (int k = 32; k >= 1; k >>= 1) mm = fmaxf(mm, __shfl_xor(mm, k, 64));
  if (lane == 0) big[wave] = mm;
  __syncthreads();
  mm = fmaxf(fmaxf(big[0], big[1]), fmaxf(big[2], big[3]));
  float e = (tid < NN) ? __expf(v - mm) : 0.0f;
#pragma unroll
  for (int k = 32; k >= 1; k >>= 1) e += __shfl_xor(e, k, 64);
  if (lane == 0) big[8 + wave] = e;
  __syncthreads();
  if (tid == 0) {
    const float es = big[8] + big[9] + big[10] + big[11];
    ws[b] = (mm + __logf(es)) - big[16];
  }
}

__global__ void crf_reduce_kernel(const float* __restrict__ wsIn,
                                  float* __restrict__ out) {
  const int tid = threadIdx.x; // 128 threads
  float v = wsIn[tid];
#pragma unroll
  for (int k = 32; k >= 1; k >>= 1) v += __shfl_xor(v, k, 64);
  __shared__ float s2[2];
  if ((tid & 63) == 0) s2[tid >> 6] = v;
  __syncthreads();
  if (tid == 0) out[0] = (s2[0] + s2[1]) * (1.0f / 128.0f);
}

extern "C" void kernel_launch(void* const* d_in, const int* in_sizes, int n_in,
                              void* d_out, int out_size, void* d_ws, size_t ws_size,
                              hipStream_t stream) {
  const float* unary = (const float*)d_in[0];
  const int* tags = (const int*)d_in[1];
  const int* lengths = (const int*)d_in[2];
  const float* trans = (const float*)d_in[3];
  float* ws = (float*)d_ws;
  float* out = (float*)d_out;

  crf_fwd_kernel<<<BB, NT, 0, stream>>>(unary, tags, lengths, trans, ws);
  crf_reduce_kernel<<<1, 128, 0, stream>>>(ws, out);
}